// Round 2
// baseline (251.096 us; speedup 1.0000x reference)
//
#include <hip/hip_runtime.h>
#include <hip/hip_bf16.h>

// AFT-Full on gfx950 — fragment-linear + MX-fp8 GEMM2 + XCD-slab scheduling.
// ew = exp(wbias) = 1 + E, |E|<=0.039: num = colsumZ + E@eKV, den = colsumK + E@eK.
// colsums exact (f32 atomics in GEMM1 epilogue); correction GEMM in fp8 e4m3 via
// mfma_scale_f32_32x32x64_f8f6f4 (scales pinned 1.0; static E*32, Z/4, /8 undo).
// Round-10: GEMM1/GEMM3 as 128x256-tile / 256-thread / 4-wave kernels, wave output
// 64x128 (acc[2][4]: 12 ds_reads feed 16 MFMA, was 8:8), ring-3 LDS (72 KB ->
// 2 blocks/CU, 2 waves/SIMD from DIFFERENT blocks): async blocks overlap one
// block's MFMA with the other's ds_read/barrier stall — breaks the phase
// serialization that capped round-9 at MfmaUtil 31% (phase = 516 MFMA + 512 read
// + 192 write + ~500 ovh cyc, serialized at 1 block/CU).  Single barrier per
// phase; vmcnt(6) AFTER the MFMA cluster (never 0 in main loop); full unroll so
// LDS slot offsets fold to ds_read immediates.

#define AS1(p) ((const __attribute__((address_space(1))) void*)(p))
#define AS3(p) ((__attribute__((address_space(3))) void*)(p))

typedef _Float16 half8 __attribute__((ext_vector_type(8)));
typedef _Float16 half4v __attribute__((ext_vector_type(4)));
typedef float floatx16 __attribute__((ext_vector_type(16)));
typedef int intx4 __attribute__((ext_vector_type(4)));
typedef int intx8 __attribute__((ext_vector_type(8)));

// f16 fragment-linear 128x64 tile (8192 halfs): [r>>5][k>>4][(k>>3)&1][r&31][k&7]
__device__ __forceinline__ long frag_off(int r, int k) {
  return (long)(((((r >> 5) * 4 + (k >> 4)) * 2 + ((k >> 3) & 1)) * 32 + (r & 31)) * 8 + (k & 7));
}
// fp8 fragment-linear 128x128 tile (16384 B)
__device__ __forceinline__ long off8(int r, int k) {
  return (long)((((((r >> 5) * 2 + ((k >> 6) & 1)) * 2 + ((k >> 4) & 1)) * 2 + ((k >> 5) & 1)) * 32 +
                 (r & 31)) * 16 + (k & 15));
}

// ---------------- prep_all ----------------
// blocks [0,1024): x -> f16 frag tiles; [1024,1536): W -> f16 tiles via LDS;
// [1536,1792): (exp(wbias)-1)*32 -> fp8 frag tiles
__global__ __launch_bounds__(256) void prep_all(
    const float* __restrict__ x, const float* __restrict__ wb, const float* __restrict__ Wq,
    const float* __restrict__ Wk, const float* __restrict__ Wv, const float* __restrict__ Wo,
    _Float16* __restrict__ x_h, char* __restrict__ E8, _Float16* __restrict__ WqkvT,
    _Float16* __restrict__ WoT) {
  __shared__ _Float16 lds[64 * 132];
  const int bid = blockIdx.x;
  const int tid = threadIdx.x;

  if (bid < 1024) {  // x -> f16 tiles
    const int tm = bid >> 4, tk = bid & 15;
    const long tbase = (long)bid * 8192;
#pragma unroll
    for (int p = 0; p < 4; ++p) {
      const int s = p * 256 + tid;
      const int r = ((s >> 8) << 5) + (s & 31);
      const int k = ((s >> 6) & 3) * 16 + ((s >> 5) & 1) * 8;
      const float* sp = x + (long)(tm * 128 + r) * 1024 + tk * 64 + k;
      const float4 v0 = *(const float4*)sp;
      const float4 v1 = *(const float4*)(sp + 4);
      half8 h;
      h[0] = (_Float16)v0.x; h[1] = (_Float16)v0.y; h[2] = (_Float16)v0.z; h[3] = (_Float16)v0.w;
      h[4] = (_Float16)v1.x; h[5] = (_Float16)v1.y; h[6] = (_Float16)v1.z; h[7] = (_Float16)v1.w;
      *(half8*)(x_h + tbase + (long)s * 8) = h;
    }
    return;
  }

  if (bid >= 1536) {  // E8: (exp(wb)-1)*32 -> fp8 frag tiles
    const int e = bid - 1536;
    const int tt = e >> 4, ts = e & 15;
    char* dst = E8 + (long)e * 16384;
#pragma unroll
    for (int p = 0; p < 16; ++p) {
      const int idx = p * 256 + tid;
      const int r = idx >> 5, k = (idx & 31) * 4;
      const float4 v = *(const float4*)(wb + (long)(tt * 128 + r) * 2048 + ts * 128 + k);
      const float e0 = (__expf(v.x) - 1.0f) * 32.0f, e1 = (__expf(v.y) - 1.0f) * 32.0f;
      const float e2 = (__expf(v.z) - 1.0f) * 32.0f, e3 = (__expf(v.w) - 1.0f) * 32.0f;
      int pk = __builtin_amdgcn_cvt_pk_fp8_f32(e0, e1, 0, false);
      pk = __builtin_amdgcn_cvt_pk_fp8_f32(e2, e3, pk, true);
      *(int*)(dst + off8(r, k)) = pk;
    }
    return;
  }

  // ---- weight tiler (f16) ----
  const int b2 = bid - 1024;
  const float* src0;
  const float* src1 = nullptr;
  _Float16* dst;
  int tn, tk, cb = 0;
  if (b2 < 128) {
    tn = b2 >> 4; tk = b2 & 15; src0 = Wq; dst = WqkvT;
  } else if (b2 < 384) {
    const int t = b2 - 128;
    tn = 8 + (t >> 4); tk = t & 15; cb = (tn - 8) * 64; src0 = Wk; src1 = Wv; dst = WqkvT;
  } else {
    const int t = b2 - 384;
    tn = t >> 4; tk = t & 15; src0 = Wo; dst = WoT;
  }
  if (!src1) {
#pragma unroll
    for (int p = 0; p < 8; ++p) {
      const int kl = p * 8 + (tid >> 5);
      const int cl = (tid & 31) * 4;
      const float4 v = *(const float4*)(src0 + (long)(tk * 64 + kl) * 1024 + tn * 128 + cl);
      half4v h;
      h[0] = (_Float16)v.x; h[1] = (_Float16)v.y; h[2] = (_Float16)v.z; h[3] = (_Float16)v.w;
      *(half4v*)(lds + kl * 132 + cl) = h;
    }
  } else {
#pragma unroll
    for (int m = 0; m < 2; ++m) {
      const float* s = m ? src1 : src0;
      const int rb = m ? 32 : 0;
#pragma unroll
      for (int p = 0; p < 4; ++p) {
        const int kl = p * 16 + (tid >> 4);
        const int cl = (tid & 15) * 4;
        const int rl = (cl >> 5) * 64 + rb + (cl & 31);
        const float4 v = *(const float4*)(s + (long)(tk * 64 + kl) * 1024 + cb + cl);
        half4v h;
        h[0] = (_Float16)v.x; h[1] = (_Float16)v.y; h[2] = (_Float16)v.z; h[3] = (_Float16)v.w;
        *(half4v*)(lds + kl * 132 + rl) = h;
      }
    }
  }
  __syncthreads();
  const long tbase = (long)(tn * 16 + tk) * 8192;
#pragma unroll
  for (int p = 0; p < 4; ++p) {
    const int s = p * 256 + tid;
    const int r = ((s >> 8) << 5) + (s & 31);
    const int kl = ((s >> 6) & 3) * 16 + ((s >> 5) & 1) * 8;
    half8 h;
#pragma unroll
    for (int j = 0; j < 8; ++j) h[j] = lds[(kl + j) * 132 + r];
    *(half8*)(dst + tbase + (long)s * 8) = h;
  }
}

// ---------------- f16 GEMM, 128x256 tile, 4 waves (64x128 each), ring-3 LDS ----------------
// K = 1024 = 32 K-halves of 32.  Slot = 24 KB (A 8 KB + B 16 KB), ring of 3 = 72 KB
// -> 2 blocks/CU.  Phase g: 12x ds_read slot g%3 -> stage half g+2 into slot (g+2)%3
// (6 loads) -> lgkmcnt(0) -> 16 MFMA -> vmcnt(6) -> barrier.  vmcnt(6) drains phase
// g-1's 6 loads (slot for phase g+1); barrier globalizes.  WAR on slot (g+2)%3 is
// safe: its readers (phase g-1) retired before phase g-1's end barrier.
template <int VM, bool STAGE>
__device__ __forceinline__ void aft_phase2(
    const _Float16* rA, const _Float16* rB, _Float16* sAd, _Float16* sBd,
    const _Float16* gA, const _Float16* gB, int lane, int wm, int wn,
    floatx16 (&acc)[2][4]) {
  half8 af[2][2], bf[4][2];
#pragma unroll
  for (int mt = 0; mt < 2; ++mt)
#pragma unroll
    for (int ks = 0; ks < 2; ++ks)
      af[mt][ks] = *(const half8*)(rA + (((wm >> 5) + mt) * 2 + ks) * 512 + lane * 8);
#pragma unroll
  for (int nt = 0; nt < 4; ++nt)
#pragma unroll
    for (int ks = 0; ks < 2; ++ks)
      bf[nt][ks] = *(const half8*)(rB + (((wn >> 5) + nt) * 2 + ks) * 512 + lane * 8);
  if (STAGE) {
#pragma unroll
    for (int p = 0; p < 2; ++p)
      __builtin_amdgcn_global_load_lds(AS1(gA + p * 4096), AS3(sAd + p * 2048), 16, 0, 0);
#pragma unroll
    for (int q = 0; q < 4; ++q)
      __builtin_amdgcn_global_load_lds(AS1(gB + (q >> 1) * 131072 + (q & 1) * 4096),
                                       AS3(sBd + q * 2048), 16, 0, 0);
  }
  asm volatile("s_waitcnt lgkmcnt(0)" ::: "memory");
  __builtin_amdgcn_s_setprio(1);
#pragma unroll
  for (int ks = 0; ks < 2; ++ks)
#pragma unroll
    for (int mt = 0; mt < 2; ++mt)
#pragma unroll
      for (int nt = 0; nt < 4; ++nt)
        acc[mt][nt] =
            __builtin_amdgcn_mfma_f32_32x32x16_f16(af[mt][ks], bf[nt][ks], acc[mt][nt], 0, 0, 0);
  __builtin_amdgcn_s_setprio(0);
  asm volatile("s_waitcnt vmcnt(%0)" ::"i"(VM) : "memory");
  __builtin_amdgcn_s_barrier();
  asm volatile("" ::: "memory");
}

// Block order: XCD x = f&7 owns m-slab [8x, 8x+8) of 128-row tiles, walks n slowly.
// MODE 0 (GEMM1): n0<1024 -> Qsig C-frag sigmoid(+bq); else K/V pairs -> Zt8 + colsums.
// MODE 2 (GEMM3): fp32 row-major store + bias0.
template <int MODE>
__global__ __launch_bounds__(256, 2) void gemm_bt2(
    const _Float16* __restrict__ A, const _Float16* __restrict__ Bt, void* __restrict__ Cv,
    const float* __restrict__ bias0, const float* __restrict__ bias1,
    const float* __restrict__ bias2, char* __restrict__ Zt8, float* __restrict__ cs) {
  __shared__ __align__(16) _Float16 ring[36864];  // A: 3x4096 halfs | B: 3x8192 halfs
  const int tid = threadIdx.x;
  const int wid = tid >> 6, lane = tid & 63;
  const int l32 = lane & 31, khalf = lane >> 5;

  const int f = blockIdx.x;
  const int j = f >> 3;
  const int bxs = (f & 7) * 8 + (j & 7);
  const int bys = j >> 3;
  const int m0 = bxs * 128, n0 = bys * 256;
  const int wm = (wid >> 1) * 64, wn = (wid & 1) * 128;

  const long thrOff = (long)(tid >> 7) * 2048 + (tid & 127) * 8;
  const _Float16* gA0 = A + (long)bxs * 131072 + thrOff;
  const _Float16* gB0 = Bt + (long)(bys * 2) * 131072 + thrOff;

  _Float16* ringB = ring + 12288;
  _Float16* sAt = ring + tid * 8;   // + slot*4096 + p*2048
  _Float16* sBt = ringB + tid * 8;  // + slot*8192 + q*2048

  // prologue: stage K-half 0 -> slot 0, K-half 1 -> slot 1 (t=0, kh=0/1)
#pragma unroll
  for (int ph = 0; ph < 2; ++ph) {
    const _Float16* ga = gA0 + ph * 1024;
    const _Float16* gb = gB0 + ph * 1024;
#pragma unroll
    for (int p = 0; p < 2; ++p)
      __builtin_amdgcn_global_load_lds(AS1(ga + p * 4096), AS3(sAt + ph * 4096 + p * 2048), 16, 0, 0);
#pragma unroll
    for (int q = 0; q < 4; ++q)
      __builtin_amdgcn_global_load_lds(AS1(gb + (q >> 1) * 131072 + (q & 1) * 4096),
                                       AS3(sBt + ph * 8192 + q * 2048), 16, 0, 0);
  }
  asm volatile("s_waitcnt vmcnt(6)" ::: "memory");
  __builtin_amdgcn_s_barrier();
  asm volatile("" ::: "memory");

  floatx16 acc[2][4] = {};

  // pairs 0..14 cover phases 0..29; pair pr stages K-halves 2pr+2, 2pr+3 (t = pr+1)
#pragma unroll
  for (int pr = 0; pr < 15; ++pr) {
    const int s0 = (2 * pr) % 3, s1 = (2 * pr + 1) % 3, s2 = (2 * pr + 2) % 3;
    const _Float16* gA = gA0 + (long)(pr + 1) * 8192;
    const _Float16* gB = gB0 + (long)(pr + 1) * 8192;
    aft_phase2<6, true>(ring + s0 * 4096, ringB + s0 * 8192, sAt + s2 * 4096, sBt + s2 * 8192,
                        gA, gB, lane, wm, wn, acc);
    aft_phase2<6, true>(ring + s1 * 4096, ringB + s1 * 8192, sAt + s0 * 4096, sBt + s0 * 8192,
                        gA + 1024, gB + 1024, lane, wm, wn, acc);
  }
  // phases 30 (slot 0), 31 (slot 1): no staging; drain
  aft_phase2<0, false>(ring + 0 * 4096, ringB + 0 * 8192, nullptr, nullptr, nullptr, nullptr,
                       lane, wm, wn, acc);
  aft_phase2<0, false>(ring + 1 * 4096, ringB + 1 * 8192, nullptr, nullptr, nullptr, nullptr,
                       lane, wm, wn, acc);

  if (MODE == 0) {
    if (n0 < 1024) {
      _Float16* Qs = (_Float16*)Cv;
#pragma unroll
      for (int mt = 0; mt < 2; ++mt) {
        const long ttile = (m0 + wm + mt * 32) >> 5;
#pragma unroll
        for (int nt = 0; nt < 4; ++nt) {
          const int col = n0 + wn + nt * 32 + l32;
          const float bb = bias0[col];
          const long base = (ttile * 32 + (((n0 + wn) >> 5) + nt)) * 1024;
#pragma unroll
          for (int q = 0; q < 4; ++q) {
            half4v o;
#pragma unroll
            for (int rr = 0; rr < 4; ++rr) {
              const float v = acc[mt][nt][q * 4 + rr] + bb;
              o[rr] = (_Float16)(1.0f / (1.0f + __expf(-v)));
            }
            *(half4v*)(Qs + base + q * 256 + lane * 4) = o;
          }
        }
      }
    } else {
      const int b = m0 >> 11;
      const int g0 = (n0 - 1024 + wn) >> 6;
#pragma unroll
      for (int p = 0; p < 2; ++p) {
        const int grp = g0 + p;
        const int ch = grp * 32 + l32;
        const float bkc = bias1[ch], bvc = bias2[ch];
        const int jn = grp * 64 + l32;  // Zt num row; den = +32 (same 128-tile)
        char* Z8 = Zt8 + (long)b * 4194304 +
                   ((long)(jn >> 7) * 16 + ((m0 & 2047) >> 7)) * 16384;
        const int jnl = jn & 127;
        float sk = 0.f, sz = 0.f;
#pragma unroll
        for (int mt = 0; mt < 2; ++mt) {
#pragma unroll
          for (int q = 0; q < 4; ++q) {
            float ekv[4], ekk[4];
#pragma unroll
            for (int rr = 0; rr < 4; ++rr) {
              const float ek = __expf(acc[mt][2 * p][q * 4 + rr] + bkc);
              const float vv = acc[mt][2 * p + 1][q * 4 + rr] + bvc;
              ekk[rr] = ek;
              ekv[rr] = ek * vv;
              sk += ek;
              sz += ek * vv;
            }
            const int sl = wm + mt * 32 + 4 * khalf + 8 * q;  // s within tile (+rr)
            int pn = __builtin_amdgcn_cvt_pk_fp8_f32(ekv[0] * 0.25f, ekv[1] * 0.25f, 0, false);
            pn = __builtin_amdgcn_cvt_pk_fp8_f32(ekv[2] * 0.25f, ekv[3] * 0.25f, pn, true);
            int pd = __builtin_amdgcn_cvt_pk_fp8_f32(ekk[0] * 0.25f, ekk[1] * 0.25f, 0, false);
            pd = __builtin_amdgcn_cvt_pk_fp8_f32(ekk[2] * 0.25f, ekk[3] * 0.25f, pd, true);
            *(int*)(Z8 + off8(jnl, sl)) = pn;
            *(int*)(Z8 + off8(jnl + 32, sl)) = pd;
          }
        }
        atomicAdd(&cs[(long)b * 2048 + ch * 2], sz);
        atomicAdd(&cs[(long)b * 2048 + ch * 2 + 1], sk);
      }
    }
    return;
  }

  // MODE 2: fp32 row-major + bias0
#pragma unroll
  for (int mt = 0; mt < 2; ++mt)
#pragma unroll
    for (int nt = 0; nt < 4; ++nt) {
      const int col = n0 + wn + nt * 32 + l32;
      const float bb = bias0[col];
#pragma unroll
      for (int reg = 0; reg < 16; ++reg) {
        const int row = m0 + wm + mt * 32 + 4 * khalf + 8 * (reg >> 2) + (reg & 3);
        ((float*)Cv)[(long)row * 1024 + col] = acc[mt][nt][reg] + bb;
      }
    }
}

// ---------------- GEMM2: fp8 correction  acc = (E*32) @ (Z/4)^T, BK=128 ----------------
// OutHead = Qsig * (csZ + accn/8) / (csK + accd/8), grid (16,16,4).
__global__ __launch_bounds__(256) void gemm2_fp8(
    const char* __restrict__ E8, const char* __restrict__ Zt8, _Float16* __restrict__ OH,
    const _Float16* __restrict__ Qsig, const float* __restrict__ cs) {
  __shared__ __align__(16) char sA[16384];
  __shared__ __align__(16) char sB[16384];
  const int tid = threadIdx.x;
  const int wave = tid >> 6, lane = tid & 63;
  const int l32 = lane & 31, khalf = lane >> 5;

  const int f = blockIdx.x + 16 * (blockIdx.y + 16 * blockIdx.z);
  const int nid = (f & 7) * 128 + (f >> 3);
  const int bxs = nid & 15, bys = (nid >> 4) & 15, bzs = nid >> 8;

  const int m0 = bxs * 128, n0 = bys * 128;
  const int wm = (wave >> 1) * 64, wn = (wave & 1) * 64;

  const char* At = E8 + (long)bxs * 16 * 16384;
  const char* Bt = Zt8 + (long)bzs * 4194304 + (long)bys * 16 * 16384;

  floatx16 acc[2][2] = {};

  for (int tk = 0; tk < 16; ++tk) {
    const char* As = At + tk * 16384 + wave * 1024 + lane * 16;
    const char* Bs = Bt + tk * 16384 + wave * 1024 + lane * 16;
#pragma unroll
    for (int c = 0; c < 4; ++c) {
      __builtin_amdgcn_global_load_lds(AS1(As + c * 4096), AS3(sA + c * 4096 + wave * 1024), 16, 0, 0);
      __builtin_amdgcn_global_load_lds(AS1(Bs + c * 4096), AS3(sB + c * 4096 + wave * 1024), 16, 0, 0);
    }
    __syncthreads();
#pragma unroll
    for (int ks = 0; ks < 2; ++ks) {
      intx8 a8[2], b8[2];
#pragma unroll
      for (int i = 0; i < 2; ++i) {
        const char* pa = sA + (((wm >> 5) + i) * 2 + ks) * 2048 + khalf * 512 + l32 * 16;
        const intx4 alo = *(const intx4*)pa;
        const intx4 ahi = *(const intx4*)(pa + 1024);
        a8[i] = __builtin_shufflevector(alo, ahi, 0, 1, 2, 3, 4, 5, 6, 7);
        const char* pb = sB + (((wn >> 5) + i) * 2 + ks) * 2048 + khalf * 512 + l32 * 16;
        const intx4 blo = *(const intx4*)pb;
        const intx4 bhi = *(const intx4*)(pb + 1024);
        b8[i] = __builtin_shufflevector(blo, bhi, 0, 1, 2, 3, 4, 5, 6, 7);
      }
#pragma unroll
      for (int mt = 0; mt < 2; ++mt)
#pragma unroll
        for (int nt = 0; nt < 2; ++nt)
          acc[mt][nt] = __builtin_amdgcn_mfma_scale_f32_32x32x64_f8f6f4(
              a8[mt], b8[nt], acc[mt][nt], 0, 0, 0, 127u, 0, 127u);
    }
    __syncthreads();
  }

  const int ch = ((n0 + wn) >> 6) * 32 + l32;
  const float2 c2 = *(const float2*)(cs + (long)bzs * 2048 + ch * 2);  // (csZ, csK)
#pragma unroll
  for (int mt = 0; mt < 2; ++mt) {
    const long ttile = (long)(bzs * 2048 + m0 + wm + mt * 32) >> 5;
    const long qbase = (ttile * 32 + ((n0 + wn) >> 6)) * 1024;
#pragma unroll
    for (int q = 0; q < 4; ++q) {
      const half4v qv = *(const half4v*)(Qsig + qbase + q * 256 + lane * 4);
#pragma unroll
      for (int rr = 0; rr < 4; ++rr) {
        const int reg = q * 4 + rr;
        const float num = c2.x + acc[mt][0][reg] * 0.125f;
        const float den = c2.y + acc[mt][1][reg] * 0.125f;
        const int r = m0 + wm + mt * 32 + 4 * khalf + 8 * q + rr;
        const int R = bzs * 2048 + r;
        const long off = ((long)(R >> 7) * 16 + (ch >> 6)) * 8192 + frag_off(R & 127, ch & 63);
        OH[off] = (_Float16)((float)qv[rr] * num / den);
      }
    }
  }
}

// ---------------- launch ----------------
extern "C" void kernel_launch(void* const* d_in, const int* in_sizes, int n_in, void* d_out,
                              int out_size, void* d_ws, size_t ws_size, hipStream_t stream) {
  const float* x = (const float*)d_in[0];
  const float* Wq = (const float*)d_in[1];
  const float* bq = (const float*)d_in[2];
  const float* Wk = (const float*)d_in[3];
  const float* bk = (const float*)d_in[4];
  const float* Wv = (const float*)d_in[5];
  const float* bv = (const float*)d_in[6];
  const float* Wo = (const float*)d_in[7];
  const float* bo = (const float*)d_in[8];
  const float* wb = (const float*)d_in[9];

  char* ws = (char*)d_ws;
  _Float16* x_h = (_Float16*)(ws + 0);              // 16 MB  (1024 f16 frag tiles)
  _Float16* WqkvT = (_Float16*)(ws + 16777216);     //  6 MB
  _Float16* WoT = (_Float16*)(ws + 23068672);       //  2 MB
  char* E8 = (char*)(ws + 25165824);                //  4 MB  (256 fp8 frag tiles)
  _Float16* Qsig = (_Float16*)(ws + 29360128);      // 16 MB  (C-frag tiles)
  char* Zt8 = (char*)(ws + 46137344);               // 16 MB  (fp8 frag tiles, 4 batches)
  _Float16* OutHead = (_Float16*)(ws + 62914560);   // 16 MB  (f16 frag tiles)
  float* cs = (float*)(ws + 79691776);              // 32 KB  (csZ,csK interleaved)

  hipMemsetAsync(cs, 0, 4 * 2048 * sizeof(float), stream);

  // prep: x tiles + weight tiles + E8 tiles
  prep_all<<<1792, 256, 0, stream>>>(x, wb, Wq, Wk, Wv, Wo, x_h, E8, WqkvT, WoT);

  // GEMM1: x @ [Wq|Wkv]; epilogue -> Qsig (C-frag), Zt8 (fp8), colsum atomics
  gemm_bt2<0><<<768, 256, 0, stream>>>(x_h, WqkvT, Qsig, bq, bk, bv, Zt8, cs);

  // GEMM2 (fp8 correction + rank-1): OutHead = Qsig*(csZ+E@Z)/(csK+E@eK)
  gemm2_fp8<<<dim3(16, 16, 4), 256, 0, stream>>>(E8, Zt8, OutHead, Qsig, cs);

  // GEMM3: out = OutHead @ Wo + bo (fp32)
  gemm_bt2<2><<<256, 256, 0, stream>>>(OutHead, WoT, d_out, bo, nullptr, nullptr, nullptr, nullptr);
}